// Round 10
// baseline (24667.549 us; speedup 1.0000x reference)
//
#include <hip/hip_runtime.h>
#include <hip/hip_bf16.h>
#include <stdint.h>
#include <stddef.h>

using bf16_t = __hip_bfloat16;
typedef __attribute__((ext_vector_type(8))) short short8;
typedef __attribute__((ext_vector_type(4))) float f32x4;

// async global->LDS 16B copy (wave-uniform LDS base + lane*16 dest pattern)
__device__ __forceinline__ void gload_lds16(void* lds, const void* g) {
  __builtin_amdgcn_global_load_lds(
      (const __attribute__((address_space(1))) unsigned int*)g,
      (__attribute__((address_space(3))) unsigned int*)lds,
      16, 0, 0);
}

// ---------------------------------------------------------------------------
// GEMM core  C[m][n] = sum_k A[m][k] * B[n][k]  (A: MxK activations, B: NxK
// weights, both bf16).  Block tile BM=32*MFRAG x 64, BK=64, 4 waves (2x2),
// wave tile (16*MFRAG) x 32.
//   A path: LDS, 2-buffer ring, 16B-chunk XOR swizzle (slot s^(row&7)) via
//           pre-swizzled global source; 1 barrier + vmcnt(0) per K-step.
//   B path: DIRECT global->VGPR fragments (bypasses LDS: halves LDS traffic,
//           the old 50% LDS-BW ceiling). Register double-buffer one tile
//           ahead via 2-phase unrolled K-loop (static reg names).
// 1-D grid, XCD-bijective swizzle: nwg % 8 == 0.
// MODE 0: obf = bf16(relu(acc+bias));  MODE 1: k-store + RK combine;
// MODE 2: RK combine + fp32 y write.
// ---------------------------------------------------------------------------
template<int MFRAG, int MODE>
__device__ __forceinline__ void gemm_core(
    const bf16_t* __restrict__ A, const bf16_t* __restrict__ B,
    const float* __restrict__ bias,
    bf16_t* __restrict__ obf,
    bf16_t* __restrict__ kout,
    float* __restrict__ yf_out,
    const float* __restrict__ y_in,
    const bf16_t* __restrict__ kp0, const bf16_t* __restrict__ kp1,
    const bf16_t* __restrict__ kp2, const bf16_t* __restrict__ kp3,
    float c0, float c1, float c2, float c3, float ccur,
    int M, int N, int K, int lgx)
{
  constexpr int BM = 32 * MFRAG;
  __shared__ __align__(16) bf16_t As[2][BM * 64];

  const int t    = threadIdx.x;
  const int lane = t & 63;
  const int wid  = t >> 6;
  const int wm   = wid >> 1;   // 0..1
  const int wn   = wid & 1;    // 0..1

  const int nwg = gridDim.x, bid = blockIdx.x;
  const int swz = (bid & 7) * (nwg >> 3) + (bid >> 3);
  const int gxm = (1 << lgx) - 1;
  const int bx  = swz & gxm;
  const int by  = swz >> lgx;
  const int bn0 = bx * 64, bm0 = by * BM;

  const int ro = lane & 15;
  const int ks = lane >> 4;

  const bf16_t* Ag = A + (size_t)bm0 * K;
  // per-lane B base: row (bn0 + wn*32 + ro), k-slot ks*8
  const bf16_t* Bcol = B + (size_t)(bn0 + wn * 32 + ro) * K + ks * 8;

  // stage A tile kt into buffer b (chunk(row,s) holds slot s^(row&7))
  auto stageA = [&](int b, int kt) {
    const int k0 = kt * 64;
#pragma unroll
    for (int r = 0; r < MFRAG; ++r) {
      int ch  = t + r * 256;
      int row = ch >> 3, s = ch & 7;
      int sl  = s ^ (row & 7);
      gload_lds16(&As[b][ch * 8], Ag + (size_t)row * K + k0 + sl * 8);
    }
  };
  // load B fragments for tile kt into regs: dst[ni*2+kk]
  auto loadB = [&](short8* dst, int kt) {
#pragma unroll
    for (int ni = 0; ni < 2; ++ni)
#pragma unroll
      for (int kk = 0; kk < 2; ++kk)
        dst[ni * 2 + kk] =
            *(const short8*)(Bcol + (size_t)ni * 16 * K + kt * 64 + kk * 32);
  };

  f32x4 acc[MFRAG][2] = {};

  auto compute = [&](const bf16_t* lds, const short8* bfr) {
#pragma unroll
    for (int kk = 0; kk < 2; ++kk) {
      short8 af[MFRAG];
      const int slot = kk * 4 + ks;
#pragma unroll
      for (int mi = 0; mi < MFRAG; ++mi) {
        int row = wm * (MFRAG * 16) + mi * 16 + ro;
        int ch  = row * 8 + (slot ^ (row & 7));
        af[mi]  = *(const short8*)&lds[ch * 8];
      }
      __builtin_amdgcn_s_setprio(1);
#pragma unroll
      for (int mi = 0; mi < MFRAG; ++mi)
#pragma unroll
        for (int ni = 0; ni < 2; ++ni)
          acc[mi][ni] = __builtin_amdgcn_mfma_f32_16x16x32_bf16(
              af[mi], bfr[ni * 2 + kk], acc[mi][ni], 0, 0, 0);
      __builtin_amdgcn_s_setprio(0);
    }
  };

  const int nt = K >> 6;               // 8 or 16 (even)
  short8 b0[4], b1[4];
  stageA(0, 0);
  loadB(b0, 0);

  for (int tt = 0; tt < nt; tt += 2) {
    // phase 0: tile tt, A-buf 0, B-regs b0
    asm volatile("s_waitcnt vmcnt(0)" ::: "memory");
    __builtin_amdgcn_s_barrier();
    asm volatile("" ::: "memory");
    {
      stageA(1, tt + 1);               // tt+1 < nt always (nt even)
      loadB(b1, tt + 1);
    }
    compute(As[0], b0);

    // phase 1: tile tt+1, A-buf 1, B-regs b1
    asm volatile("s_waitcnt vmcnt(0)" ::: "memory");
    __builtin_amdgcn_s_barrier();
    asm volatile("" ::: "memory");
    if (tt + 2 < nt) {
      stageA(0, tt + 2);
      loadB(b0, tt + 2);
    }
    compute(As[1], b1);
  }

  // ---- epilogue -----------------------------------------------------------
  const int rb = bm0 + wm * (MFRAG * 16);
  const int cb = bn0 + wn * 32;
#pragma unroll
  for (int mi = 0; mi < MFRAG; ++mi) {
#pragma unroll
    for (int ni = 0; ni < 2; ++ni) {
      const int col = cb + ni * 16 + ro;
      const float bv = bias[col];
#pragma unroll
      for (int r = 0; r < 4; ++r) {
        const int row = rb + mi * 16 + (lane >> 4) * 4 + r;
        const size_t idx = (size_t)row * N + col;
        float v = acc[mi][ni][r] + bv;
        if (MODE == 0) {
          obf[idx] = __float2bfloat16(fmaxf(v, 0.f));
        } else {
          if (MODE == 1) kout[idx] = __float2bfloat16(v);
          float z = y_in[idx] + ccur * v;
          if (kp0) z += c0 * __bfloat162float(kp0[idx]);
          if (kp1) z += c1 * __bfloat162float(kp1[idx]);
          if (kp2) z += c2 * __bfloat162float(kp2[idx]);
          if (kp3) z += c3 * __bfloat162float(kp3[idx]);
          if (MODE == 2) yf_out[idx] = z;
          obf[idx] = __float2bfloat16(z);
        }
      }
    }
  }
}

#define GEMM_ARGS                                                           \
    const bf16_t* A, const bf16_t* B, const float* bias, bf16_t* obf,       \
    bf16_t* kout, float* yf_out, const float* y_in,                         \
    const bf16_t* kp0, const bf16_t* kp1, const bf16_t* kp2,                \
    const bf16_t* kp3, float c0, float c1, float c2, float c3, float ccur,  \
    int M, int N, int K, int lgx
#define GEMM_PASS A,B,bias,obf,kout,yf_out,y_in,kp0,kp1,kp2,kp3,c0,c1,c2,c3,ccur,M,N,K,lgx

// plain (extern "C") kernel names so rocprof CSV parses
extern "C" __global__ void __launch_bounds__(256, 2) g12relu(GEMM_ARGS) {
  gemm_core<4, 0>(GEMM_PASS);
}
extern "C" __global__ void __launch_bounds__(256, 2) g3kcomb(GEMM_ARGS) {
  gemm_core<2, 1>(GEMM_PASS);
}
extern "C" __global__ void __launch_bounds__(256, 2) g3ycomb(GEMM_ARGS) {
  gemm_core<2, 2>(GEMM_PASS);
}

// ---------------------------------------------------------------------------
// single fused init: weights f32->bf16, y=x, yb=bf16(x)
// ---------------------------------------------------------------------------
extern "C" __global__ void init_all(const float* __restrict__ x,
                         const float* __restrict__ W1,
                         const float* __restrict__ W2,
                         const float* __restrict__ W3,
                         bf16_t* __restrict__ W1b, bf16_t* __restrict__ W2b,
                         bf16_t* __restrict__ W3b,
                         float* __restrict__ y, bf16_t* __restrict__ yb,
                         int n1, int n2, int n3, int ny)
{
  const int gt = blockIdx.x * blockDim.x + threadIdx.x;
  const int gs = gridDim.x * blockDim.x;
  auto cvt4 = [&](const float* in, bf16_t* outp, int n) {
    for (int i = gt * 4; i < n; i += gs * 4) {
      float4 v = *(const float4*)(in + i);
      bf16_t o[4] = {__float2bfloat16(v.x), __float2bfloat16(v.y),
                     __float2bfloat16(v.z), __float2bfloat16(v.w)};
      *(uint64_t*)(outp + i) = *(uint64_t*)o;
    }
  };
  cvt4(W1, W1b, n1);
  cvt4(W2, W2b, n2);
  cvt4(W3, W3b, n3);
  for (int i = gt * 4; i < ny; i += gs * 4) {
    float4 v = *(const float4*)(x + i);
    *(float4*)(y + i) = v;
    bf16_t o[4] = {__float2bfloat16(v.x), __float2bfloat16(v.y),
                   __float2bfloat16(v.z), __float2bfloat16(v.w)};
    *(uint64_t*)(yb + i) = *(uint64_t*)o;
  }
}

// ---------------------------------------------------------------------------
extern "C" void kernel_launch(void* const* d_in, const int* in_sizes, int n_in,
                              void* d_out, int out_size, void* d_ws, size_t ws_size,
                              hipStream_t stream)
{
  const float* x  = (const float*)d_in[0];
  const float* W1 = (const float*)d_in[1];
  const float* b1 = (const float*)d_in[2];
  const float* W2 = (const float*)d_in[3];
  const float* b2 = (const float*)d_in[4];
  const float* W3 = (const float*)d_in[5];
  const float* b3 = (const float*)d_in[6];

  const int data   = in_sizes[6];            // 512
  const int hidden = in_sizes[2];            // 1024
  const int batch  = in_sizes[0] / data;     // 4096

  char* ws = (char*)d_ws;
  size_t off = 0;
  auto alloc = [&](size_t bytes) -> void* {
    off = (off + 255) & ~(size_t)255;
    void* p = ws + off;
    off += bytes;
    return p;
  };
  const size_t nyd = (size_t)batch * data;
  const size_t nh  = (size_t)batch * hidden;

  float*  y   = (float*)alloc(nyd * 4);
  bf16_t* yb  = (bf16_t*)alloc(nyd * 2);
  bf16_t* zb  = (bf16_t*)alloc(nyd * 2);
  bf16_t* h1  = (bf16_t*)alloc(nh * 2);
  bf16_t* h2  = (bf16_t*)alloc(nh * 2);
  bf16_t* k1  = (bf16_t*)alloc(nyd * 2);
  bf16_t* k2  = (bf16_t*)alloc(nyd * 2);
  bf16_t* k3  = (bf16_t*)alloc(nyd * 2);
  bf16_t* k4  = (bf16_t*)alloc(nyd * 2);
  bf16_t* k5  = (bf16_t*)alloc(nyd * 2);
  bf16_t* W1b = (bf16_t*)alloc((size_t)hidden * data * 2);
  bf16_t* W2b = (bf16_t*)alloc((size_t)hidden * hidden * 2);
  bf16_t* W3b = (bf16_t*)alloc((size_t)data * hidden * 2);

  init_all<<<2048, 256, 0, stream>>>(x, W1, W2, W3, W1b, W2b, W3b, y, yb,
                                     hidden * data, hidden * hidden,
                                     data * hidden, (int)nyd);

  const double hh = 1.0 / 64.0;
  const float hA21 = (float)(hh * (1.0/5.0));
  const float hA31 = (float)(hh * (3.0/40.0)),    hA32 = (float)(hh * (9.0/40.0));
  const float hA41 = (float)(hh * (44.0/45.0)),   hA42 = (float)(hh * (-56.0/15.0)),
              hA43 = (float)(hh * (32.0/9.0));
  const float hA51 = (float)(hh * (19372.0/6561.0)),  hA52 = (float)(hh * (-25360.0/2187.0)),
              hA53 = (float)(hh * (64448.0/6561.0)),  hA54 = (float)(hh * (-212.0/729.0));
  const float hA61 = (float)(hh * (9017.0/3168.0)),   hA62 = (float)(hh * (-355.0/33.0)),
              hA63 = (float)(hh * (46732.0/5247.0)),  hA64 = (float)(hh * (49.0/176.0)),
              hA65 = (float)(hh * (-5103.0/18656.0));
  const float hB1 = (float)(hh * (35.0/384.0)),   hB3 = (float)(hh * (500.0/1113.0)),
              hB4 = (float)(hh * (125.0/192.0)),  hB5 = (float)(hh * (-2187.0/6784.0)),
              hB6 = (float)(hh * (11.0/84.0));

  const dim3 blk(256);
  const int gridH = (hidden / 64) * (batch / 128);  // 16*32 = 512, lgx=4
  const int grid3 = (data / 64) * (batch / 64);     //  8*64 = 512, lgx=3
  const int lgxH = 4, lgx3 = 3;

  auto mlp_front = [&](const bf16_t* zin) {
    g12relu<<<gridH, blk, 0, stream>>>(
        zin, W1b, b1, h1, nullptr, nullptr, nullptr,
        nullptr, nullptr, nullptr, nullptr, 0.f, 0.f, 0.f, 0.f, 0.f,
        batch, hidden, data, lgxH);
    g12relu<<<gridH, blk, 0, stream>>>(
        h1, W2b, b2, h2, nullptr, nullptr, nullptr,
        nullptr, nullptr, nullptr, nullptr, 0.f, 0.f, 0.f, 0.f, 0.f,
        batch, hidden, hidden, lgxH);
  };

  auto stage_k = [&](bf16_t* kout, const bf16_t* p0, float cc0, const bf16_t* p1, float cc1,
                     const bf16_t* p2, float cc2, const bf16_t* p3, float cc3, float ccur) {
    g3kcomb<<<grid3, blk, 0, stream>>>(
        h2, W3b, b3, zb, kout, nullptr, y,
        p0, p1, p2, p3, cc0, cc1, cc2, cc3, ccur,
        batch, data, hidden, lgx3);
  };

  for (int step = 0; step < 64; ++step) {
    mlp_front(yb);
    stage_k(k1, nullptr, 0.f, nullptr, 0.f, nullptr, 0.f, nullptr, 0.f, hA21);
    mlp_front(zb);
    stage_k(k2, k1, hA31, nullptr, 0.f, nullptr, 0.f, nullptr, 0.f, hA32);
    mlp_front(zb);
    stage_k(k3, k1, hA41, k2, hA42, nullptr, 0.f, nullptr, 0.f, hA43);
    mlp_front(zb);
    stage_k(k4, k1, hA51, k2, hA52, k3, hA53, nullptr, 0.f, hA54);
    mlp_front(zb);
    stage_k(k5, k1, hA61, k2, hA62, k3, hA63, k4, hA64, hA65);
    mlp_front(zb);
    float* yf = (step == 63) ? (float*)d_out : y;
    g3ycomb<<<grid3, blk, 0, stream>>>(
        h2, W3b, b3, yb, nullptr, yf, y,
        k1, k3, k4, k5, hB1, hB3, hB4, hB5, hB6,
        batch, data, hidden, lgx3);
  }
}

// Round 11
// 18653.986 us; speedup vs baseline: 1.3224x; 1.3224x over previous
//
#include <hip/hip_runtime.h>
#include <hip/hip_bf16.h>
#include <stdint.h>
#include <stddef.h>

using bf16_t = __hip_bfloat16;
typedef __attribute__((ext_vector_type(8))) short short8;
typedef __attribute__((ext_vector_type(4))) float f32x4;

// async global->LDS 16B copy (wave-uniform LDS base + lane*16 dest pattern)
__device__ __forceinline__ void gload_lds16(void* lds, const void* g) {
  __builtin_amdgcn_global_load_lds(
      (const __attribute__((address_space(1))) unsigned int*)g,
      (__attribute__((address_space(3))) unsigned int*)lds,
      16, 0, 0);
}

// ---------------------------------------------------------------------------
// GEMM  C[m][n] = sum_k A[m][k] * B[n][k].  A: MxK activations (bf16, LDS
// path).  B: weights PRE-PACKED in MFMA-fragment order (bf16, direct->VGPR):
//   Bp elem offset of frag(ntile, kt, kk, lane) =
//       ((ntile*(K/64) + kt)*2 + kk)*512 + lane*8
// so each wave fragment load is wave-uniform base + lane*16 -> one coalesced
// 1KB global_load_dwordx4.  B never touches LDS (halves LDS + staging).
// Block tile 64x64, BK=64, 4 waves (2x2), wave tile 32x32; A: 2-buffer LDS
// ring w/ 16B-chunk XOR swizzle (slot s^(row&7)) via pre-swizzled source;
// B: register-double-buffered (2-phase unrolled loop, static reg names).
// vmcnt: explicit vmcnt(4) retires A-stage only (2 oldest); compiler inserts
// counted waits for B-register uses.  1 barrier per K-step.
// 1-D grid, XCD-bijective swizzle: nwg % 8 == 0; batch rows partition per
// XCD identically across all GEMMs -> producer/consumer L2-local.
// MODE 0: obf=bf16(relu(acc+bias));  MODE 1: k-store + RK combine;
// MODE 2: RK combine + fp32 y write.
// ---------------------------------------------------------------------------
template<int MODE>
__device__ __forceinline__ void gemm_core(
    const bf16_t* __restrict__ A, const bf16_t* __restrict__ Bp,
    const float* __restrict__ bias,
    bf16_t* __restrict__ obf,
    bf16_t* __restrict__ kout,
    float* __restrict__ yf_out,
    const float* __restrict__ y_in,
    const bf16_t* __restrict__ kp0, const bf16_t* __restrict__ kp1,
    const bf16_t* __restrict__ kp2, const bf16_t* __restrict__ kp3,
    float c0, float c1, float c2, float c3, float ccur,
    int M, int N, int K, int lgx)
{
  __shared__ __align__(16) bf16_t As[2][64 * 64];

  const int t    = threadIdx.x;
  const int lane = t & 63;
  const int wid  = t >> 6;
  const int wm   = wid >> 1;   // 0..1
  const int wn   = wid & 1;    // 0..1

  const int nwg = gridDim.x, bid = blockIdx.x;
  const int swz = (bid & 7) * (nwg >> 3) + (bid >> 3);
  const int gxm = (1 << lgx) - 1;
  const int bx  = swz & gxm;
  const int by  = swz >> lgx;
  const int bn0 = bx * 64, bm0 = by * 64;

  const bf16_t* Ag = A + (size_t)bm0 * K;
  const int ntk = K >> 6;              // K-tiles (8 or 16, even)
  // wave's two B n-tile bases (elems): ntile = bx*4 + wn*2 + ni
  const bf16_t* Bw = Bp + ((size_t)(bx * 4 + wn * 2) * ntk * 2) * 512
                        + (size_t)lane * 8;

  // stage A tile kt into buffer b (chunk(row,s) holds slot s^(row&7))
  auto stageA = [&](int b, int kt) {
    const int k0 = kt * 64;
#pragma unroll
    for (int r = 0; r < 2; ++r) {      // 512 chunks / 256 threads
      int ch  = t + r * 256;
      int row = ch >> 3, s = ch & 7;
      int sl  = s ^ (row & 7);
      gload_lds16(&As[b][ch * 8], Ag + (size_t)row * K + k0 + sl * 8);
    }
  };
  // load wave's 4 B fragments for tile kt: dst[ni*2+kk]
  auto loadB = [&](short8* dst, int kt) {
#pragma unroll
    for (int ni = 0; ni < 2; ++ni)
#pragma unroll
      for (int kk = 0; kk < 2; ++kk)
        dst[ni * 2 + kk] = *(const short8*)
            (Bw + ((size_t)ni * ntk * 2 + kt * 2 + kk) * 512);
  };

  f32x4 acc[2][2] = {};
  const int ro = lane & 15;
  const int ks = lane >> 4;

  auto compute = [&](const bf16_t* lds, const short8* bfr) {
#pragma unroll
    for (int kk = 0; kk < 2; ++kk) {
      short8 af[2];
      const int slot = kk * 4 + ks;
#pragma unroll
      for (int mi = 0; mi < 2; ++mi) {
        int row = wm * 32 + mi * 16 + ro;
        int ch  = row * 8 + (slot ^ (row & 7));
        af[mi]  = *(const short8*)&lds[ch * 8];
      }
      __builtin_amdgcn_s_setprio(1);
#pragma unroll
      for (int mi = 0; mi < 2; ++mi)
#pragma unroll
        for (int ni = 0; ni < 2; ++ni)
          acc[mi][ni] = __builtin_amdgcn_mfma_f32_16x16x32_bf16(
              af[mi], bfr[ni * 2 + kk], acc[mi][ni], 0, 0, 0);
      __builtin_amdgcn_s_setprio(0);
    }
  };

  short8 b0[4], b1[4];
  stageA(0, 0);
  loadB(b0, 0);

  for (int tt = 0; tt < ntk; tt += 2) {
    // phase 0: tile tt (A-buf 0, regs b0)
    asm volatile("s_waitcnt vmcnt(4)" ::: "memory");   // retire A(tt) only
    __builtin_amdgcn_s_barrier();
    asm volatile("" ::: "memory");
    stageA(1, tt + 1);                 // ntk even -> tt+1 < ntk
    loadB(b1, tt + 1);
    compute(As[0], b0);

    // phase 1: tile tt+1 (A-buf 1, regs b1)
    asm volatile("s_waitcnt vmcnt(4)" ::: "memory");   // retire A(tt+1)
    __builtin_amdgcn_s_barrier();
    asm volatile("" ::: "memory");
    if (tt + 2 < ntk) {
      stageA(0, tt + 2);
      loadB(b0, tt + 2);
    }
    compute(As[1], b1);
  }

  // ---- epilogue -----------------------------------------------------------
  const int rb = bm0 + wm * 32;
  const int cb = bn0 + wn * 32;
#pragma unroll
  for (int mi = 0; mi < 2; ++mi) {
#pragma unroll
    for (int ni = 0; ni < 2; ++ni) {
      const int col = cb + ni * 16 + ro;
      const float bv = bias[col];
#pragma unroll
      for (int r = 0; r < 4; ++r) {
        const int row = rb + mi * 16 + (lane >> 4) * 4 + r;
        const size_t idx = (size_t)row * N + col;
        float v = acc[mi][ni][r] + bv;
        if (MODE == 0) {
          obf[idx] = __float2bfloat16(fmaxf(v, 0.f));
        } else {
          if (MODE == 1) kout[idx] = __float2bfloat16(v);
          float z = y_in[idx] + ccur * v;
          if (kp0) z += c0 * __bfloat162float(kp0[idx]);
          if (kp1) z += c1 * __bfloat162float(kp1[idx]);
          if (kp2) z += c2 * __bfloat162float(kp2[idx]);
          if (kp3) z += c3 * __bfloat162float(kp3[idx]);
          if (MODE == 2) yf_out[idx] = z;
          obf[idx] = __float2bfloat16(z);
        }
      }
    }
  }
}

#define GEMM_ARGS                                                           \
    const bf16_t* A, const bf16_t* B, const float* bias, bf16_t* obf,       \
    bf16_t* kout, float* yf_out, const float* y_in,                         \
    const bf16_t* kp0, const bf16_t* kp1, const bf16_t* kp2,                \
    const bf16_t* kp3, float c0, float c1, float c2, float c3, float ccur,  \
    int M, int N, int K, int lgx
#define GEMM_PASS A,B,bias,obf,kout,yf_out,y_in,kp0,kp1,kp2,kp3,c0,c1,c2,c3,ccur,M,N,K,lgx

extern "C" __global__ void __launch_bounds__(256, 4) g12relu(GEMM_ARGS) {
  gemm_core<0>(GEMM_PASS);
}
extern "C" __global__ void __launch_bounds__(256, 4) g3kcomb(GEMM_ARGS) {
  gemm_core<1>(GEMM_PASS);
}
extern "C" __global__ void __launch_bounds__(256, 4) g3ycomb(GEMM_ARGS) {
  gemm_core<2>(GEMM_PASS);
}

// ---------------------------------------------------------------------------
// init: pack weights f32 -> bf16 fragment order; y=x, yb=bf16(x).
// pack chunk c (8 elems): lane=c&63; kk=(c>>6)&1; kt=(c>>7)%(K/64);
// ntile=c/((K/64)*128); src row = ntile*16+(lane&15),
// src col = kt*64+kk*32+(lane>>4)*8; dst = c*8 (coalesced write).
// ---------------------------------------------------------------------------
__device__ __forceinline__ void pack_w(const float* __restrict__ W,
                                       bf16_t* __restrict__ Wp,
                                       int N, int K, int gt, int gs)
{
  const int nchunk = (N * K) / 8;
  const int ktn = K >> 6;
  for (int c = gt; c < nchunk; c += gs) {
    int lane  = c & 63;
    int kk    = (c >> 6) & 1;
    int kt    = (c >> 7) % ktn;
    int ntile = c / (ktn * 128);
    const float* src = W + (size_t)(ntile * 16 + (lane & 15)) * K
                         + kt * 64 + kk * 32 + (lane >> 4) * 8;
    bf16_t o[8];
#pragma unroll
    for (int j = 0; j < 8; ++j) o[j] = __float2bfloat16(src[j]);
    *(short8*)(Wp + (size_t)c * 8) = *(short8*)o;
  }
}

extern "C" __global__ void init_all(const float* __restrict__ x,
                         const float* __restrict__ W1,
                         const float* __restrict__ W2,
                         const float* __restrict__ W3,
                         bf16_t* __restrict__ W1p, bf16_t* __restrict__ W2p,
                         bf16_t* __restrict__ W3p,
                         float* __restrict__ y, bf16_t* __restrict__ yb,
                         int hid, int data, int ny)
{
  const int gt = blockIdx.x * blockDim.x + threadIdx.x;
  const int gs = gridDim.x * blockDim.x;
  pack_w(W1, W1p, hid, data, gt, gs);
  pack_w(W2, W2p, hid, hid, gt, gs);
  pack_w(W3, W3p, data, hid, gt, gs);
  for (int i = gt * 4; i < ny; i += gs * 4) {
    float4 v = *(const float4*)(x + i);
    *(float4*)(y + i) = v;
    bf16_t o[4] = {__float2bfloat16(v.x), __float2bfloat16(v.y),
                   __float2bfloat16(v.z), __float2bfloat16(v.w)};
    *(uint64_t*)(yb + i) = *(uint64_t*)o;
  }
}

// ---------------------------------------------------------------------------
extern "C" void kernel_launch(void* const* d_in, const int* in_sizes, int n_in,
                              void* d_out, int out_size, void* d_ws, size_t ws_size,
                              hipStream_t stream)
{
  const float* x  = (const float*)d_in[0];
  const float* W1 = (const float*)d_in[1];
  const float* b1 = (const float*)d_in[2];
  const float* W2 = (const float*)d_in[3];
  const float* b2 = (const float*)d_in[4];
  const float* W3 = (const float*)d_in[5];
  const float* b3 = (const float*)d_in[6];

  const int data   = in_sizes[6];            // 512
  const int hidden = in_sizes[2];            // 1024
  const int batch  = in_sizes[0] / data;     // 4096

  char* ws = (char*)d_ws;
  size_t off = 0;
  auto alloc = [&](size_t bytes) -> void* {
    off = (off + 255) & ~(size_t)255;
    void* p = ws + off;
    off += bytes;
    return p;
  };
  const size_t nyd = (size_t)batch * data;
  const size_t nh  = (size_t)batch * hidden;

  float*  y   = (float*)alloc(nyd * 4);
  bf16_t* yb  = (bf16_t*)alloc(nyd * 2);
  bf16_t* zb  = (bf16_t*)alloc(nyd * 2);
  bf16_t* h1  = (bf16_t*)alloc(nh * 2);
  bf16_t* h2  = (bf16_t*)alloc(nh * 2);
  bf16_t* k1  = (bf16_t*)alloc(nyd * 2);
  bf16_t* k2  = (bf16_t*)alloc(nyd * 2);
  bf16_t* k3  = (bf16_t*)alloc(nyd * 2);
  bf16_t* k4  = (bf16_t*)alloc(nyd * 2);
  bf16_t* k5  = (bf16_t*)alloc(nyd * 2);
  bf16_t* W1p = (bf16_t*)alloc((size_t)hidden * data * 2);
  bf16_t* W2p = (bf16_t*)alloc((size_t)hidden * hidden * 2);
  bf16_t* W3p = (bf16_t*)alloc((size_t)data * hidden * 2);

  init_all<<<2048, 256, 0, stream>>>(x, W1, W2, W3, W1p, W2p, W3p, y, yb,
                                     hidden, data, (int)nyd);

  const double hh = 1.0 / 64.0;
  const float hA21 = (float)(hh * (1.0/5.0));
  const float hA31 = (float)(hh * (3.0/40.0)),    hA32 = (float)(hh * (9.0/40.0));
  const float hA41 = (float)(hh * (44.0/45.0)),   hA42 = (float)(hh * (-56.0/15.0)),
              hA43 = (float)(hh * (32.0/9.0));
  const float hA51 = (float)(hh * (19372.0/6561.0)),  hA52 = (float)(hh * (-25360.0/2187.0)),
              hA53 = (float)(hh * (64448.0/6561.0)),  hA54 = (float)(hh * (-212.0/729.0));
  const float hA61 = (float)(hh * (9017.0/3168.0)),   hA62 = (float)(hh * (-355.0/33.0)),
              hA63 = (float)(hh * (46732.0/5247.0)),  hA64 = (float)(hh * (49.0/176.0)),
              hA65 = (float)(hh * (-5103.0/18656.0));
  const float hB1 = (float)(hh * (35.0/384.0)),   hB3 = (float)(hh * (500.0/1113.0)),
              hB4 = (float)(hh * (125.0/192.0)),  hB5 = (float)(hh * (-2187.0/6784.0)),
              hB6 = (float)(hh * (11.0/84.0));

  const dim3 blk(256);
  const int gridH = (hidden / 64) * (batch / 64);   // 16*64 = 1024, lgx=4
  const int grid3 = (data / 64) * (batch / 64);     //  8*64 = 512,  lgx=3
  const int lgxH = 4, lgx3 = 3;

  auto mlp_front = [&](const bf16_t* zin) {
    g12relu<<<gridH, blk, 0, stream>>>(
        zin, W1p, b1, h1, nullptr, nullptr, nullptr,
        nullptr, nullptr, nullptr, nullptr, 0.f, 0.f, 0.f, 0.f, 0.f,
        batch, hidden, data, lgxH);
    g12relu<<<gridH, blk, 0, stream>>>(
        h1, W2p, b2, h2, nullptr, nullptr, nullptr,
        nullptr, nullptr, nullptr, nullptr, 0.f, 0.f, 0.f, 0.f, 0.f,
        batch, hidden, hidden, lgxH);
  };

  auto stage_k = [&](bf16_t* kout, const bf16_t* p0, float cc0, const bf16_t* p1, float cc1,
                     const bf16_t* p2, float cc2, const bf16_t* p3, float cc3, float ccur) {
    g3kcomb<<<grid3, blk, 0, stream>>>(
        h2, W3p, b3, zb, kout, nullptr, y,
        p0, p1, p2, p3, cc0, cc1, cc2, cc3, ccur,
        batch, data, hidden, lgx3);
  };

  for (int step = 0; step < 64; ++step) {
    mlp_front(yb);
    stage_k(k1, nullptr, 0.f, nullptr, 0.f, nullptr, 0.f, nullptr, 0.f, hA21);
    mlp_front(zb);
    stage_k(k2, k1, hA31, nullptr, 0.f, nullptr, 0.f, nullptr, 0.f, hA32);
    mlp_front(zb);
    stage_k(k3, k1, hA41, k2, hA42, nullptr, 0.f, nullptr, 0.f, hA43);
    mlp_front(zb);
    stage_k(k4, k1, hA51, k2, hA52, k3, hA53, nullptr, 0.f, hA54);
    mlp_front(zb);
    stage_k(k5, k1, hA61, k2, hA62, k3, hA63, k4, hA64, hA65);
    mlp_front(zb);
    float* yf = (step == 63) ? (float*)d_out : y;
    g3ycomb<<<grid3, blk, 0, stream>>>(
        h2, W3p, b3, yb, nullptr, yf, y,
        k1, k3, k4, k5, hB1, hB3, hB4, hB5, hB6,
        batch, data, hidden, lgx3);
  }
}